// Round 1
// baseline (34.089 us; speedup 1.0000x reference)
//
#include <hip/hip_runtime.h>

#define BB 4
#define CC 8
#define HW 4096
#define L2E 1.4426950408889634f

// ws float offsets
#define PART_OFF 0        // [B][8 blocks][44 partials]  (36 tri-Gram + 8 rowsum)
#define MP_OFF   1408     // [B][64]   M' = attn*Wv + 2I
#define CV_OFF   1664     // [B][8]    c = attn*bv
#define PQ_OFF   1792     // [B][4096] pq
#define PKV_OFF  18176    // [B][4096][2] interleaved (pk*log2e, pv)
// total 50944 floats = ~200 KB of ws

// ---------------- Kernel 1: Gram + rowsum partials, PAM q/k/v vectors ----------------
__global__ __launch_bounds__(256) void k1_stats(
    const float* __restrict__ x,
    const float* __restrict__ pwq, const float* __restrict__ pbq,
    const float* __restrict__ pwk, const float* __restrict__ pbk,
    const float* __restrict__ pwv, const float* __restrict__ pbv,
    float* __restrict__ ws)
{
  const int b = blockIdx.x >> 3, blk = blockIdx.x & 7;
  const int tid = threadIdx.x;
  const float* xb = x + b * CC * HW;

  float wqv[CC], wkv[CC], wvv[CC];
  #pragma unroll
  for (int c = 0; c < CC; ++c) { wqv[c] = pwq[c]; wkv[c] = pwk[c]; wvv[c] = pwv[c]; }
  const float bq0 = pbq[0], bk0 = pbk[0], bv0 = pbv[0];

  float acc[44];
  #pragma unroll
  for (int i = 0; i < 44; ++i) acc[i] = 0.f;

  #pragma unroll
  for (int it = 0; it < 2; ++it) {
    const int n = blk * 512 + it * 256 + tid;
    float xv[CC];
    #pragma unroll
    for (int c = 0; c < CC; ++c) xv[c] = xb[c * HW + n];
    float pq = bq0, pk = bk0, pv = bv0;
    #pragma unroll
    for (int c = 0; c < CC; ++c) {
      pq = fmaf(wqv[c], xv[c], pq);
      pk = fmaf(wkv[c], xv[c], pk);
      pv = fmaf(wvv[c], xv[c], pv);
    }
    ws[PQ_OFF + b * HW + n] = pq;
    const int o = PKV_OFF + (b * HW + n) * 2;
    ws[o]     = pk * L2E;
    ws[o + 1] = pv;
    int k = 0;
    #pragma unroll
    for (int c = 0; c < CC; ++c) {
      #pragma unroll
      for (int d = c; d < CC; ++d) { acc[k] = fmaf(xv[c], xv[d], acc[k]); ++k; }
    }
    #pragma unroll
    for (int c = 0; c < CC; ++c) acc[36 + c] += xv[c];
  }

  // butterfly reduce across the 64-lane wave (every lane ends with the sum)
  #pragma unroll
  for (int i = 0; i < 44; ++i) {
    float v = acc[i];
    #pragma unroll
    for (int off = 32; off > 0; off >>= 1) v += __shfl_xor(v, off, 64);
    acc[i] = v;
  }

  __shared__ float part[4][44];
  const int wv_ = tid >> 6, ln = tid & 63;
  if (ln == 0) {
    #pragma unroll
    for (int i = 0; i < 44; ++i) part[wv_][i] = acc[i];  // static indices (no scratch)
  }
  __syncthreads();
  if (tid < 44) {
    const float t = part[0][tid] + part[1][tid] + part[2][tid] + part[3][tid];
    ws[PART_OFF + (b * 8 + blk) * 44 + tid] = t;
  }
}

// ---------------- Kernel 2: CAM 8x8 softmax -> M' and c-vec ----------------
__global__ __launch_bounds__(64) void k2_attn(
    const float* __restrict__ cwq, const float* __restrict__ cbq,
    const float* __restrict__ cwk, const float* __restrict__ cbk,
    const float* __restrict__ cwv, const float* __restrict__ cbv,
    float* __restrict__ ws)
{
  const int b = blockIdx.x, t = threadIdx.x;
  const int c = t >> 3, d = t & 7;
  __shared__ float sums[44], Gl[64], Ll[64], Al[64];

  if (t < 44) {
    float s = 0.f;
    for (int blk = 0; blk < 8; ++blk) s += ws[PART_OFF + (b * 8 + blk) * 44 + t];
    sums[t] = s;
  }
  __syncthreads();
  {
    const int lo = min(c, d), hi = max(c, d);
    Gl[t] = sums[lo * 8 + hi - lo * (lo + 1) / 2];
  }
  __syncthreads();

  float qs = 0.f, ks = 0.f;
  #pragma unroll
  for (int e = 0; e < 8; ++e) {
    qs = fmaf(cwq[c * 8 + e], sums[36 + e], qs);
    ks = fmaf(cwk[d * 8 + e], sums[36 + e], ks);
  }
  float A = 0.f;
  #pragma unroll
  for (int e = 0; e < 8; ++e) {
    float inner = 0.f;
    #pragma unroll
    for (int f = 0; f < 8; ++f) inner = fmaf(Gl[e * 8 + f], cwk[d * 8 + f], inner);
    A = fmaf(cwq[c * 8 + e], inner, A);
  }
  const float L = A + qs * cbk[d] + cbq[c] * ks + 4096.f * cbq[c] * cbk[d];
  Ll[t] = L;
  __syncthreads();

  float mx = -INFINITY;
  #pragma unroll
  for (int f = 0; f < 8; ++f) mx = fmaxf(mx, Ll[c * 8 + f]);
  float ssum = 0.f;
  #pragma unroll
  for (int f = 0; f < 8; ++f) ssum += __expf(Ll[c * 8 + f] - mx);
  Al[t] = __expf(L - mx) / ssum;
  __syncthreads();

  float M = 0.f;
  #pragma unroll
  for (int f = 0; f < 8; ++f) M = fmaf(Al[c * 8 + f], cwv[f * 8 + d], M);
  if (d == c) M += 2.f;                 // +2I: residual x appears in both CAM and PAM
  ws[MP_OFF + b * 64 + t] = M;
  if (d == 0) {
    float cvv = 0.f;
    #pragma unroll
    for (int f = 0; f < 8; ++f) cvv = fmaf(Al[c * 8 + f], cbv[f], cvv);
    ws[CV_OFF + b * 8 + c] = cvv;
  }
}

// ---------------- Kernel 3: rank-1 PAM softmax + fused epilogue ----------------
__global__ __launch_bounds__(256) void k3_pam_out(
    const float* __restrict__ x, const float* __restrict__ ws,
    float* __restrict__ out)
{
  const int b = blockIdx.x >> 6, tile = blockIdx.x & 63;
  const int n0 = tile * 64;
  const int tid = threadIdx.x, seg = tid >> 6, ln = tid & 63;

  __shared__ __align__(16) float pkv[HW * 2];   // 32 KB interleaved (pk2, pv)
  __shared__ float redd[4][64], redn[4][64], outp[64];

  const float4* s4 = (const float4*)(ws + PKV_OFF + b * HW * 2);
  float4* d4 = (float4*)pkv;
  #pragma unroll
  for (int i = 0; i < 8; ++i) d4[i * 256 + tid] = s4[i * 256 + tid];

  const float a = ws[PQ_OFF + b * HW + n0 + ln];
  __syncthreads();

  float den = 0.f, num = 0.f;
  const int m0 = seg * 1024;
  #pragma unroll 8
  for (int m = m0; m < m0 + 1024; ++m) {
    const float pk2 = pkv[2 * m];      // wave-uniform LDS read (broadcast)
    const float pv  = pkv[2 * m + 1];
    const float e = __builtin_amdgcn_exp2f(a * pk2);   // exp(pq*pk), |arg|<~26: safe
    den += e;
    num = fmaf(e, pv, num);
  }
  redd[seg][ln] = den;
  redn[seg][ln] = num;
  __syncthreads();
  if (tid < 64) {
    const float D = redd[0][tid] + redd[1][tid] + redd[2][tid] + redd[3][tid];
    const float N = redn[0][tid] + redn[1][tid] + redn[2][tid] + redn[3][tid];
    outp[tid] = N / D;
  }
  __syncthreads();

  // epilogue: out[c,n] = M'[c,:]·x[:,n] + c_vec[c] + out_p[n]
  float xv[8];
  #pragma unroll
  for (int d = 0; d < 8; ++d) xv[d] = x[(b * 8 + d) * HW + n0 + ln];
  const float op = outp[ln];
  const float* Mp = ws + MP_OFF + b * 64;   // c1/c2 wave-uniform -> scalar loads
  const float* cv = ws + CV_OFF + b * 8;
  const int c1 = seg, c2 = seg + 4;
  float o1 = cv[c1] + op, o2 = cv[c2] + op;
  #pragma unroll
  for (int d = 0; d < 8; ++d) {
    o1 = fmaf(Mp[c1 * 8 + d], xv[d], o1);
    o2 = fmaf(Mp[c2 * 8 + d], xv[d], o2);
  }
  out[(b * 8 + c1) * HW + n0 + ln] = o1;
  out[(b * 8 + c2) * HW + n0 + ln] = o2;
}

extern "C" void kernel_launch(void* const* d_in, const int* in_sizes, int n_in,
                              void* d_out, int out_size, void* d_ws, size_t ws_size,
                              hipStream_t stream) {
  const float* x   = (const float*)d_in[0];
  const float* cwq = (const float*)d_in[1];
  const float* cbq = (const float*)d_in[2];
  const float* cwk = (const float*)d_in[3];
  const float* cbk = (const float*)d_in[4];
  const float* cwv = (const float*)d_in[5];
  const float* cbv = (const float*)d_in[6];
  const float* pwq = (const float*)d_in[7];
  const float* pbq = (const float*)d_in[8];
  const float* pwk = (const float*)d_in[9];
  const float* pbk = (const float*)d_in[10];
  const float* pwv = (const float*)d_in[11];
  const float* pbv = (const float*)d_in[12];
  float* ws  = (float*)d_ws;
  float* out = (float*)d_out;

  hipLaunchKernelGGL(k1_stats, dim3(32), dim3(256), 0, stream,
                     x, pwq, pbq, pwk, pbk, pwv, pbv, ws);
  hipLaunchKernelGGL(k2_attn, dim3(4), dim3(64), 0, stream,
                     cwq, cbq, cwk, cbk, cwv, cbv, ws);
  hipLaunchKernelGGL(k3_pam_out, dim3(256), dim3(256), 0, stream,
                     x, ws, out);
}

// Round 4
// 23.822 us; speedup vs baseline: 1.4310x; 1.4310x over previous
//
#include <hip/hip_runtime.h>

#define CC 8
#define HW 4096
#define L2E 1.4426950408889634f

// ws float offsets
#define PART_OFF 0        // [4][16][44] Gram/rowsum partials
#define PQ_OFF   4096     // [4][4096] pq
#define PK2_OFF  20480    // [4][4096] pk * log2(e)
#define PV_OFF   36864    // [4][4096] pv

typedef __attribute__((ext_vector_type(4))) float f32x4;

// ---------------- Kernel 1: Gram + rowsum partials, PAM q/k/v vectors ----------------
__global__ __launch_bounds__(256) void k1_stats(
    const float* __restrict__ x,
    const float* __restrict__ pwq, const float* __restrict__ pbq,
    const float* __restrict__ pwk, const float* __restrict__ pbk,
    const float* __restrict__ pwv, const float* __restrict__ pbv,
    float* __restrict__ ws)
{
  const int b = blockIdx.x >> 4, chunk = blockIdx.x & 15;
  const int tid = threadIdx.x;
  const int n = chunk * 256 + tid;
  const float* xb = x + b * CC * HW;

  float wqv[CC], wkv[CC], wvv[CC];
  #pragma unroll
  for (int c = 0; c < CC; ++c) { wqv[c] = pwq[c]; wkv[c] = pwk[c]; wvv[c] = pwv[c]; }

  float xv[CC];
  #pragma unroll
  for (int c = 0; c < CC; ++c) xv[c] = xb[c * HW + n];

  float pq = pbq[0], pk = pbk[0], pv = pbv[0];
  #pragma unroll
  for (int c = 0; c < CC; ++c) {
    pq = fmaf(wqv[c], xv[c], pq);
    pk = fmaf(wkv[c], xv[c], pk);
    pv = fmaf(wvv[c], xv[c], pv);
  }
  ws[PQ_OFF  + b * HW + n] = pq;
  ws[PK2_OFF + b * HW + n] = pk * L2E;
  ws[PV_OFF  + b * HW + n] = pv;

  float acc[44];
  {
    int k = 0;
    #pragma unroll
    for (int c = 0; c < CC; ++c) {
      #pragma unroll
      for (int d = c; d < CC; ++d) { acc[k] = xv[c] * xv[d]; ++k; }
    }
    #pragma unroll
    for (int c = 0; c < CC; ++c) acc[36 + c] = xv[c];
  }

  // butterfly reduce across the 64-lane wave
  #pragma unroll
  for (int i = 0; i < 44; ++i) {
    float v = acc[i];
    #pragma unroll
    for (int off = 32; off > 0; off >>= 1) v += __shfl_xor(v, off, 64);
    acc[i] = v;
  }

  __shared__ float part[4][44];
  const int wv_ = tid >> 6, ln = tid & 63;
  if (ln == 0) {
    #pragma unroll
    for (int i = 0; i < 44; ++i) part[wv_][i] = acc[i];
  }
  __syncthreads();
  if (tid < 44) {
    const float t = part[0][tid] + part[1][tid] + part[2][tid] + part[3][tid];
    ws[PART_OFF + (b * 16 + chunk) * 44 + tid] = t;
  }
}

// ---------------- Kernel 2: PAM rank-1 softmax (scalar-pipe feed) + CAM + epilogue ----
__global__ __launch_bounds__(1024) void k3_main(
    const float* __restrict__ x,
    const float* __restrict__ cwq, const float* __restrict__ cbq,
    const float* __restrict__ cwk, const float* __restrict__ cbk,
    const float* __restrict__ cwv, const float* __restrict__ cbv,
    const float* __restrict__ ws, float* __restrict__ out)
{
  const int b = blockIdx.x >> 6, tile = blockIdx.x & 63;
  const int n0 = tile * 64;
  const int t = threadIdx.x, ln = t & 63;
  const int seg = __builtin_amdgcn_readfirstlane(t >> 6);   // wave id 0..15, SGPR

  __shared__ float redd[16][64], redn[16][64];
  __shared__ float sums[44], Gl[64], Ll[64], Al[64], Mp[64], cvs[8], outp[64];

  const float a = ws[PQ_OFF + b * HW + n0 + ln];            // per-lane pq

  // wave-uniform scalar pointers into this wave's 256-m segment
  const float* pkp = ws + PK2_OFF + b * HW + seg * 256;
  const float* pvp = ws + PV_OFF  + b * HW + seg * 256;

  float d0 = 0, d1 = 0, d2 = 0, d3 = 0;
  float m0 = 0, m1 = 0, m2 = 0, m3 = 0;

  for (int ch = 0; ch < 16; ++ch) {                         // 16 chunks x 16 m = 256 m
    f32x4 k0, k1, k2, k3, v0, v1, v2, v3;
    // SINGLE asm block: all 8 s_loads AND the waitcnt together, so every
    // consumer's SSA input is defined by the block containing the waitcnt
    // (split blocks let the scheduler hoist exp2/fma past the waitcnt ->
    // garbage SGPRs -> NaN; that was the round-3 failure).
    // "=&s" early-clobber: outputs must not alias the pointer inputs
    // (first s_load would clobber the base address -> round-2 fault).
    asm volatile(
      "s_load_dwordx4 %0, %8, 0x0\n\t"
      "s_load_dwordx4 %1, %8, 0x10\n\t"
      "s_load_dwordx4 %2, %8, 0x20\n\t"
      "s_load_dwordx4 %3, %8, 0x30\n\t"
      "s_load_dwordx4 %4, %9, 0x0\n\t"
      "s_load_dwordx4 %5, %9, 0x10\n\t"
      "s_load_dwordx4 %6, %9, 0x20\n\t"
      "s_load_dwordx4 %7, %9, 0x30\n\t"
      "s_waitcnt lgkmcnt(0)"
      : "=&s"(k0), "=&s"(k1), "=&s"(k2), "=&s"(k3),
        "=&s"(v0), "=&s"(v1), "=&s"(v2), "=&s"(v3)
      : "s"(pkp), "s"(pvp));
    pkp += 16; pvp += 16;

#define GRP(kg, vg, dd, nn) {                               \
    float e0 = __builtin_amdgcn_exp2f(a * kg[0]);           \
    float e1 = __builtin_amdgcn_exp2f(a * kg[1]);           \
    float e2 = __builtin_amdgcn_exp2f(a * kg[2]);           \
    float e3 = __builtin_amdgcn_exp2f(a * kg[3]);           \
    dd += ((e0 + e1) + (e2 + e3));                          \
    nn = fmaf(e0, vg[0], nn); nn = fmaf(e1, vg[1], nn);     \
    nn = fmaf(e2, vg[2], nn); nn = fmaf(e3, vg[3], nn); }

    GRP(k0, v0, d0, m0)
    GRP(k1, v1, d1, m1)
    GRP(k2, v2, d2, m2)
    GRP(k3, v3, d3, m3)
#undef GRP
  }

  redd[seg][ln] = (d0 + d1) + (d2 + d3);
  redn[seg][ln] = (m0 + m1) + (m2 + m3);
  __syncthreads();

  // ---- wave 0: per-pixel PAM result + CAM 8x8 softmax ----
  if (t < 64) {
    float D = 0.f, N = 0.f;
    #pragma unroll
    for (int s = 0; s < 16; ++s) { D += redd[s][t]; N += redn[s][t]; }
    outp[t] = N / D;
  }
  if (t < 44) {
    float s = 0.f;
    for (int ch = 0; ch < 16; ++ch) s += ws[PART_OFF + (b * 16 + ch) * 44 + t];
    sums[t] = s;
  }
  __syncthreads();

  const int c = ln >> 3, d = ln & 7;
  if (t < 64) {
    const int lo = min(c, d), hi = max(c, d);
    Gl[t] = sums[lo * 8 + hi - lo * (lo + 1) / 2];
  }
  __syncthreads();

  float Lv = 0.f;
  if (t < 64) {
    float qs = 0.f, ks = 0.f;
    #pragma unroll
    for (int e = 0; e < 8; ++e) {
      qs = fmaf(cwq[c * 8 + e], sums[36 + e], qs);
      ks = fmaf(cwk[d * 8 + e], sums[36 + e], ks);
    }
    float A = 0.f;
    #pragma unroll
    for (int e = 0; e < 8; ++e) {
      float inner = 0.f;
      #pragma unroll
      for (int f = 0; f < 8; ++f) inner = fmaf(Gl[e * 8 + f], cwk[d * 8 + f], inner);
      A = fmaf(cwq[c * 8 + e], inner, A);
    }
    Lv = A + qs * cbk[d] + cbq[c] * ks + 4096.f * cbq[c] * cbk[d];
    Ll[t] = Lv;
  }
  __syncthreads();

  if (t < 64) {
    float mx = -INFINITY;
    #pragma unroll
    for (int f = 0; f < 8; ++f) mx = fmaxf(mx, Ll[c * 8 + f]);
    float ssum = 0.f;
    #pragma unroll
    for (int f = 0; f < 8; ++f) ssum += __expf(Ll[c * 8 + f] - mx);
    Al[t] = __expf(Lv - mx) / ssum;
  }
  __syncthreads();

  if (t < 64) {
    float M = 0.f;
    #pragma unroll
    for (int f = 0; f < 8; ++f) M = fmaf(Al[c * 8 + f], cwv[f * 8 + d], M);
    if (d == c) M += 2.f;            // +2I: residual x appears in both CAM and PAM
    Mp[t] = M;
    if (d == 0) {
      float cvv = 0.f;
      #pragma unroll
      for (int f = 0; f < 8; ++f) cvv = fmaf(Al[c * 8 + f], cbv[f], cvv);
      cvs[c] = cvv;
    }
  }
  __syncthreads();

  // ---- epilogue: wave w (0..7) writes channel w for all 64 pixels ----
  if (t < 512) {
    const int w = seg;
    float xv[8];
    #pragma unroll
    for (int dd = 0; dd < 8; ++dd) xv[dd] = x[(b * 8 + dd) * HW + n0 + ln];
    float o = cvs[w] + outp[ln];
    #pragma unroll
    for (int dd = 0; dd < 8; ++dd) o = fmaf(Mp[w * 8 + dd], xv[dd], o);
    out[(b * 8 + w) * HW + n0 + ln] = o;
  }
}

extern "C" void kernel_launch(void* const* d_in, const int* in_sizes, int n_in,
                              void* d_out, int out_size, void* d_ws, size_t ws_size,
                              hipStream_t stream) {
  const float* x   = (const float*)d_in[0];
  const float* cwq = (const float*)d_in[1];
  const float* cbq = (const float*)d_in[2];
  const float* cwk = (const float*)d_in[3];
  const float* cbk = (const float*)d_in[4];
  const float* cwv = (const float*)d_in[5];
  const float* cbv = (const float*)d_in[6];
  const float* pwq = (const float*)d_in[7];
  const float* pbq = (const float*)d_in[8];
  const float* pwk = (const float*)d_in[9];
  const float* pbk = (const float*)d_in[10];
  const float* pwv = (const float*)d_in[11];
  const float* pbv = (const float*)d_in[12];
  float* ws  = (float*)d_ws;
  float* out = (float*)d_out;

  hipLaunchKernelGGL(k1_stats, dim3(64), dim3(256), 0, stream,
                     x, pwq, pbq, pwk, pbk, pwv, pbv, ws);
  hipLaunchKernelGGL(k3_main, dim3(256), dim3(1024), 0, stream,
                     x, cwq, cbq, cwk, cbk, cwv, cbv, ws, out);
}